// Round 17
// baseline (48.863 us; speedup 1.0000x reference)
//
#include <hip/hip_runtime.h>
#include <math.h>

namespace {

constexpr int B = 4, C = 64, O = 64, H = 128, W = 128, K2 = 9;
constexpr int HW = H * W;
constexpr int PIX = 128;   // fallback tile
constexpr int STR = 64;    // strip width (output px per row per block)
// window: rows ho0-1..ho0+3 (2 output rows), cols wo0-2..wo0+64
constexpr int WROWS = 5, WCOLS = STR + 3, WCELLS = WROWS * WCOLS;  // 5x67 = 335 cells

typedef __attribute__((ext_vector_type(8))) short short8v;
typedef __attribute__((ext_vector_type(4))) float f32x4;
typedef __attribute__((ext_vector_type(2))) float f32x2;
typedef __attribute__((ext_vector_type(4))) unsigned u32x4;

__device__ __forceinline__ unsigned f2bf(float f) {
    unsigned u = __float_as_uint(f);
    return (u + 0x7FFFu + ((u >> 16) & 1u)) >> 16;
}
// packed f32x2 -> bf16x2 (RNE), single instruction
__device__ __forceinline__ unsigned cvtpk(float lo, float hi) {
    unsigned r;
    asm("v_cvt_pk_bf16_f32 %0, %1, %2" : "=v"(r) : "v"(lo), "v"(hi));
    return r;
}
// unpack bf16-pair dword -> f32x2 (lo = even channel)
__device__ __forceinline__ f32x2 up2(unsigned d) {
    f32x2 r;
    r[0] = __uint_as_float(d << 16);
    r[1] = __uint_as_float(d & 0xffff0000u);
    return r;
}
// swizzled byte offset: 128-B rows, XOR bank swizzle
__device__ __forceinline__ int swz(int r, int off) {
    return (r << 7) + (off ^ ((r & 7) << 4));
}

// workspace: packed weight fragments only
constexpr size_t WSW_OFF = 0;        // 4608 * 16 B  (main conv W-frags)
constexpr size_t WSA_OFF = 73728;    // 2304 * 16 B  (offset/mod conv A-frags)
constexpr size_t WS_NEED = 110592;

// ================= K0: pack weights into bf16 MFMA-fragment layout =================
__global__ void k0_pack(const float* __restrict__ w, const float* __restrict__ ow,
                        const float* __restrict__ mw, unsigned char* __restrict__ ws)
{
    const int id = blockIdx.x * 256 + threadIdx.x;
    if (id < 4608) {
        // wsW[k][ks][ot][lane]: o = ot*16+(lane&15), cb = ks*32+(lane>>4)*8
        const int k = id >> 9, rem = id & 511, ks = rem >> 8, r2 = rem & 255;
        const int ot = r2 >> 6, lane = r2 & 63;
        const int o = ot * 16 + (lane & 15), cb = ks * 32 + (lane >> 4) * 8;
        unsigned pk[4];
        #pragma unroll
        for (int e = 0; e < 4; ++e)
            pk[e] = f2bf(w[(o * C + cb + 2 * e) * 9 + k])
                  | (f2bf(w[(o * C + cb + 2 * e + 1) * 9 + k]) << 16);
        *(uint4*)(ws + WSW_OFF + (size_t)id * 16) = make_uint4(pk[0], pk[1], pk[2], pk[3]);
    } else if (id < 6912) {
        // wsA[k][ks][mt][lane]: r = mt*16+(lane&15) (27 rows used, pad 32)
        const int id2 = id - 4608;
        const int k = id2 >> 8, rem = id2 & 255, ks = rem >> 7, r2 = rem & 127;
        const int mt = r2 >> 6, lane = r2 & 63;
        const int r = mt * 16 + (lane & 15), cb = ks * 32 + (lane >> 4) * 8;
        unsigned pk[4];
        #pragma unroll
        for (int e = 0; e < 4; ++e) {
            float v0 = 0.f, v1 = 0.f;
            const int c0 = cb + 2 * e;
            if (r < 18)      { v0 = ow[(r * C + c0) * 9 + k];        v1 = ow[(r * C + c0 + 1) * 9 + k]; }
            else if (r < 27) { v0 = mw[((r - 18) * C + c0) * 9 + k]; v1 = mw[((r - 18) * C + c0 + 1) * 9 + k]; }
            pk[e] = f2bf(v0) | (f2bf(v1) << 16);
        }
        *(uint4*)(ws + WSA_OFF + (size_t)id2 * 16) = make_uint4(pk[0], pk[1], pk[2], pk[3]);
    }
}

// ====== fused: 2 output rows x 64-px strip; 5x67 window; af amortized over rows ======
__global__ __launch_bounds__(256, 3)
void dcn_fused15(const float* __restrict__ x, const float* __restrict__ bias,
                 const float* __restrict__ ob, const float* __restrict__ mb,
                 const unsigned char* __restrict__ ws, float* __restrict__ out)
{
    __shared__ __align__(16) unsigned char sW[WCELLS * 128]; // bf16 window, 42880 B
    __shared__ float offL[2 * 18 * STR];                      // sy/sx per row, 9216 B

    const int tid = threadIdx.x;
    const int lane = tid & 63, wv = tid >> 6;
    const int lrow = lane & 15, lk = lane >> 4;

    // XCD-aware bijective swizzle (512 % 8 == 0)
    const int raw = blockIdx.x;
    const int bid = (raw & 7) * 64 + (raw >> 3);
    const int b = bid >> 7;
    const int r2_ = bid & 127;
    const int ho0 = (r2_ >> 1) << 1;     // even row; block covers ho0, ho0+1
    const int wo0 = (r2_ & 1) << 6;

    const float* __restrict__ xb = x + b * C * HW;

    // ---- stage window: rows ho0-1..ho0+3, cols wo0-2..wo0+64, 64 ch, bf16, ONCE ----
    for (int t = tid; t < 2 * WCELLS; t += 256) {      // 670 units (cell, 32-ch half)
        const int cell = t >> 1, chalf = t & 1;
        const int row = cell / WCOLS, col = cell - row * WCOLS;
        const int y = ho0 - 1 + row, xg = wo0 - 2 + col;
        const bool v = (y >= 0) & (y < H) & (xg >= 0) & (xg < W);
        const float vf = v ? 1.f : 0.f;
        const float* __restrict__ xp = xb + (v ? (y * W + xg) : 0);
        #pragma unroll
        for (int q = 0; q < 4; ++q) {
            unsigned pk[4];
            #pragma unroll
            for (int e = 0; e < 4; ++e) {
                const int c0 = chalf * 32 + q * 8 + 2 * e;
                pk[e] = cvtpk(vf * xp[c0 * HW], vf * xp[(c0 + 1) * HW]);
            }
            *(uint4*)(sW + swz(cell, chalf * 64 + q * 16)) = make_uint4(pk[0], pk[1], pk[2], pk[3]);
        }
    }
    __syncthreads();   // #1: window ready

    // ---- phase A MFMA: both rows sequentially; wave owns px-cols wv*16.. ----
    float mmr[2];
    #pragma unroll
    for (int rr = 0; rr < 2; ++rr) {
        f32x4 oacc[2];
        #pragma unroll
        for (int mt = 0; mt < 2; ++mt)
            #pragma unroll
            for (int j = 0; j < 4; ++j) oacc[mt][j] = 0.f;

        #pragma unroll
        for (int k = 0; k < 9; ++k) {
            const int ky = k / 3, kx = k - ky * 3;
            // output row ho0+rr, tap y = ho0+rr-1+ky = window row rr+ky; col <= 66 OK
            const int cellb = (rr + ky) * WCOLS + (wv * 16 + lrow) + kx + 1;
            #pragma unroll
            for (int ks = 0; ks < 2; ++ks) {
                short8v bf = *(const short8v*)(sW + swz(cellb, ks * 64 + lk * 16));
                #pragma unroll
                for (int mt = 0; mt < 2; ++mt) {
                    short8v af = *(const short8v*)(ws + WSA_OFF +
                        (size_t)((((k * 2 + ks) * 2 + mt) * 64 + lane)) * 16);
                    oacc[mt] = __builtin_amdgcn_mfma_f32_16x16x32_bf16(af, bf, oacc[mt], 0, 0, 0);
                }
            }
        }

        float mpart = 0.f;
        {
            const int pc = wv * 16 + lrow;
            #pragma unroll
            for (int mt = 0; mt < 2; ++mt) {
                #pragma unroll
                for (int j = 0; j < 4; ++j) {
                    const int r = mt * 16 + lk * 4 + j;
                    const float val = oacc[mt][j];
                    if (r < 9)       offL[(rr * 18 + r) * STR + pc] = (float)(ho0 + rr) + ob[r] + val;
                    else if (r < 18) offL[(rr * 18 + r) * STR + pc] = (float)(wo0 + pc) + ob[r] + val;
                    else if (r < 27) mpart += 1.f / (1.f + __expf(-(val + mb[r - 18])));
                }
            }
        }
        mpart += __shfl_xor(mpart, 16);
        mpart += __shfl_xor(mpart, 32);
        mmr[rr] = mpart * (1.f / 9.f);
    }
    __syncthreads();   // #2: offL ready (window untouched) — last barrier

    // ---- phase B: per-wave, barrier-free. Wave owns px = wv*16+lrow, BOTH rows. ----
    const int px = wv * 16 + lrow;

    f32x4 acc[2][4];   // [row][o-tile]
    #pragma unroll
    for (int rr = 0; rr < 2; ++rr)
        #pragma unroll
        for (int ot = 0; ot < 4; ++ot)
            #pragma unroll
            for (int j = 0; j < 4; ++j) acc[rr][ot][j] = 0.f;

    // af double-buffer pipeline: one 8-fragment set per tap serves BOTH rows (16 MFMAs)
    short8v afq[8], afn[8];
    #pragma unroll
    for (int i = 0; i < 8; ++i)
        afq[i] = *(const short8v*)(ws + WSW_OFF + (size_t)(i * 64 + lane) * 16);

    #pragma unroll
    for (int k = 0; k < 9; ++k) {
        // prefetch next tap's af fragments early
        if (k < 8) {
            #pragma unroll
            for (int i = 0; i < 8; ++i)
                afn[i] = *(const short8v*)(ws + WSW_OFF +
                    (size_t)(((k + 1) * 8 + i) * 64 + lane) * 16);
        }

        #pragma unroll
        for (int rr = 0; rr < 2; ++rr) {
            const float syv = offL[(rr * 18 + k) * STR + px];
            const float sxv = offL[(rr * 18 + 9 + k) * STR + px];
            const float fy = floorf(syv), fx = floorf(sxv);
            const float wy1 = syv - fy, wx1 = sxv - fx;
            const float wy0 = 1.f - wy1, wx0 = 1.f - wx1;
            const int y0 = (int)fy, x0 = (int)fx;
            const int wrow = y0 - (ho0 - 1), cw = x0 - (wo0 - 2);
            const bool inw = (wrow >= 0) & (wrow <= WROWS - 2) & (cw >= 0) & (cw <= WCOLS - 2);
            const float u00 = wy0 * wx0, u01 = wy0 * wx1;
            const float u10 = wy1 * wx0, u11 = wy1 * wx1;

            short8v bfrag[2];
            if (__builtin_expect(inw, 1)) {
                const int c00 = wrow * WCOLS + cw;
                #pragma unroll
                for (int ks = 0; ks < 2; ++ks) {
                    const int chOff = ks * 64 + lk * 16;
                    const uint4 d00 = *(const uint4*)(sW + swz(c00,             chOff));
                    const uint4 d01 = *(const uint4*)(sW + swz(c00 + 1,         chOff));
                    const uint4 d10 = *(const uint4*)(sW + swz(c00 + WCOLS,     chOff));
                    const uint4 d11 = *(const uint4*)(sW + swz(c00 + WCOLS + 1, chOff));
                    // packed bilinear per channel-pair, cvt_pk to bf16x2
                    auto bil = [&](unsigned a, unsigned bb, unsigned c, unsigned d) -> unsigned {
                        f32x2 sacc = up2(a);
                        sacc *= u00;
                        sacc += up2(bb) * u01;
                        sacc += up2(c)  * u10;
                        sacc += up2(d)  * u11;
                        return cvtpk(sacc[0], sacc[1]);
                    };
                    u32x4 wvv;
                    wvv[0] = bil(d00.x, d01.x, d10.x, d11.x);
                    wvv[1] = bil(d00.y, d01.y, d10.y, d11.y);
                    wvv[2] = bil(d00.z, d01.z, d10.z, d11.z);
                    wvv[3] = bil(d00.w, d01.w, d10.w, d11.w);
                    bfrag[ks] = __builtin_bit_cast(short8v, wvv);
                }
            } else {
                // exact global fallback (validity-weighted, clamped) — cold path
                const float vy0 = (y0 >= 0 && y0 < H) ? 1.f : 0.f;
                const float vy1 = (y0 + 1 >= 0 && y0 + 1 < H) ? 1.f : 0.f;
                const float vx0 = (x0 >= 0 && x0 < W) ? 1.f : 0.f;
                const float vx1 = (x0 + 1 >= 0 && x0 + 1 < W) ? 1.f : 0.f;
                const int cy0 = min(max(y0, 0), H - 1), cy1 = min(max(y0 + 1, 0), H - 1);
                const int cx0 = min(max(x0, 0), W - 1), cx1 = min(max(x0 + 1, 0), W - 1);
                const int l00 = cy0 * W + cx0, l01 = cy0 * W + cx1;
                const int l10 = cy1 * W + cx0, l11 = cy1 * W + cx1;
                const float g00 = u00 * vy0 * vx0, g01 = u01 * vy0 * vx1;
                const float g10 = u10 * vy1 * vx0, g11 = u11 * vy1 * vx1;
                #pragma unroll
                for (int ks = 0; ks < 2; ++ks) {
                    #pragma unroll
                    for (int j = 0; j < 8; ++j) {
                        const float* __restrict__ xc = xb + (ks * 32 + lk * 8 + j) * HW;
                        const float sv = g00 * xc[l00] + g01 * xc[l01]
                                       + g10 * xc[l10] + g11 * xc[l11];
                        bfrag[ks][j] = (short)f2bf(sv);
                    }
                }
            }

            // 8 MFMAs for this row (af fragments shared across rows)
            #pragma unroll
            for (int i = 0; i < 8; ++i)
                acc[rr][i & 3] = __builtin_amdgcn_mfma_f32_16x16x32_bf16(
                    afq[i], bfrag[i >> 2], acc[rr][i & 3], 0, 0, 0);
        }

        if (k < 8) {
            #pragma unroll
            for (int i = 0; i < 8; ++i) afq[i] = afn[i];
        }
    }

    // ---- epilogue: modulate, bias, store (both rows) ----
    #pragma unroll
    for (int rr = 0; rr < 2; ++rr) {
        #pragma unroll
        for (int ot = 0; ot < 4; ++ot) {
            #pragma unroll
            for (int j = 0; j < 4; ++j) {
                const int o = ot * 16 + lk * 4 + j;
                out[(b * O + o) * HW + (ho0 + rr) * W + wo0 + px] =
                    acc[rr][ot][j] * mmr[rr] + bias[o];
            }
        }
    }
}

// ================= fallback (round-2 kernel, used if ws too small) =================
__global__ __launch_bounds__(256, 2)
void dcn_fallback(const float* __restrict__ x, const float* __restrict__ weight,
                  const float* __restrict__ bias, const float* __restrict__ ow,
                  const float* __restrict__ ob, const float* __restrict__ mw,
                  const float* __restrict__ mb, float* __restrict__ out)
{
    __shared__ __align__(16) unsigned char sT[PIX * 128];
    __shared__ float offL[32 * PIX];
    __shared__ float mmL[PIX];

    const int tid = threadIdx.x;
    const int lane = tid & 63;
    const int wv = tid >> 6;
    const int bid = (blockIdx.x & 7) * 64 + (blockIdx.x >> 3);
    const int b = bid >> 7;
    const int ho = bid & 127;
    const float* __restrict__ xb = x + (size_t)b * C * HW;
    const int p = tid & 127, half = tid >> 7, wo = p;
    const int lrow = lane & 15, lk = lane >> 4;

    f32x4 oacc[2][2];
    #pragma unroll
    for (int mt = 0; mt < 2; ++mt)
        #pragma unroll
        for (int nt = 0; nt < 2; ++nt)
            #pragma unroll
            for (int j = 0; j < 4; ++j) oacc[mt][nt][j] = 0.0f;

    #pragma unroll
    for (int k = 0; k < K2; ++k) {
        const int ky = k / 3, kx = k % 3;
        short8v afrA[2][2];
        #pragma unroll
        for (int ks = 0; ks < 2; ++ks)
            #pragma unroll
            for (int mt = 0; mt < 2; ++mt) {
                const int r = mt * 16 + lrow, cb = ks * 32 + lk * 8;
                #pragma unroll
                for (int j = 0; j < 8; ++j) {
                    float wvv = 0.0f;
                    if (r < 18)      wvv = ow[((size_t)(r * C + cb + j)) * 9 + k];
                    else if (r < 27) wvv = mw[((size_t)((r - 18) * C + cb + j)) * 9 + k];
                    afrA[ks][mt][j] = (short)f2bf(wvv);
                }
            }
        {
            const int y = ho - 1 + ky, xx = wo - 1 + kx;
            const bool v = (y >= 0) & (y < H) & (xx >= 0) & (xx < W);
            const float vf = v ? 1.0f : 0.0f;
            const float* __restrict__ xp = xb + (v ? (y * W + xx) : 0);
            #pragma unroll
            for (int q = 0; q < 4; ++q) {
                unsigned pk[4];
                #pragma unroll
                for (int e = 0; e < 4; ++e) {
                    const int c0 = half * 32 + q * 8 + e * 2;
                    pk[e] = f2bf(vf * xp[(size_t)c0 * HW]) | (f2bf(vf * xp[(size_t)(c0 + 1) * HW]) << 16);
                }
                *(uint4*)(sT + swz(p, half * 64 + q * 16)) = make_uint4(pk[0], pk[1], pk[2], pk[3]);
            }
        }
        __syncthreads();
        #pragma unroll
        for (int ks = 0; ks < 2; ++ks)
            #pragma unroll
            for (int nt = 0; nt < 2; ++nt) {
                const int pc = wv * 32 + nt * 16 + lrow;
                short8v bfr = *(const short8v*)(sT + swz(pc, ks * 64 + lk * 16));
                #pragma unroll
                for (int mt = 0; mt < 2; ++mt)
                    oacc[mt][nt] = __builtin_amdgcn_mfma_f32_16x16x32_bf16(afrA[ks][mt], bfr, oacc[mt][nt], 0, 0, 0);
            }
        __syncthreads();
    }

    #pragma unroll
    for (int mt = 0; mt < 2; ++mt)
        #pragma unroll
        for (int nt = 0; nt < 2; ++nt)
            #pragma unroll
            for (int j = 0; j < 4; ++j) {
                const int r = mt * 16 + lk * 4 + j;
                const int pc = wv * 32 + nt * 16 + lrow;
                float bv = 0.0f;
                if (r < 18)      bv = ob[r];
                else if (r < 27) bv = mb[r - 18];
                offL[r * PIX + pc] = oacc[mt][nt][j] + bv;
            }
    __syncthreads();

    float sy[K2], sx[K2];
    #pragma unroll
    for (int k = 0; k < K2; ++k) {
        sy[k] = (float)ho + offL[k * PIX + p];
        sx[k] = (float)wo + offL[(9 + k) * PIX + p];
    }
    if (half == 0) {
        float mm = 0.0f;
        #pragma unroll
        for (int k = 0; k < K2; ++k)
            mm += 1.0f / (1.0f + __expf(-offL[(18 + k) * PIX + p]));
        mmL[p] = mm * (1.0f / 9.0f);
    }

    f32x4 acc[8];
    #pragma unroll
    for (int nt = 0; nt < 8; ++nt)
        #pragma unroll
        for (int j = 0; j < 4; ++j) acc[nt][j] = 0.0f;

    #pragma unroll
    for (int k = 0; k < K2; ++k) {
        short8v afr[2];
        #pragma unroll
        for (int ks = 0; ks < 2; ++ks) {
            const int o = wv * 16 + lrow, cb = ks * 32 + lk * 8;
            #pragma unroll
            for (int j = 0; j < 8; ++j)
                afr[ks][j] = (short)f2bf(weight[((size_t)(o * C + cb + j)) * 9 + k]);
        }
        {
            const float fy = floorf(sy[k]), fx = floorf(sx[k]);
            const float wy1 = sy[k] - fy, wx1 = sx[k] - fx;
            const float wy0 = 1.0f - wy1, wx0 = 1.0f - wx1;
            const int y0 = (int)fy, x0 = (int)fx, y1 = y0 + 1, x1 = x0 + 1;
            const float vy0 = (y0 >= 0 && y0 < H) ? 1.0f : 0.0f;
            const float vy1 = (y1 >= 0 && y1 < H) ? 1.0f : 0.0f;
            const float vx0 = (x0 >= 0 && x0 < W) ? 1.0f : 0.0f;
            const float vx1 = (x1 >= 0 && x1 < W) ? 1.0f : 0.0f;
            const int cy0 = min(max(y0, 0), H - 1), cy1 = min(max(y1, 0), H - 1);
            const int cx0 = min(max(x0, 0), W - 1), cx1 = min(max(x1, 0), W - 1);
            const int l00 = cy0 * W + cx0, l01 = cy0 * W + cx1;
            const int l10 = cy1 * W + cx0, l11 = cy1 * W + cx1;
            const float w00 = wy0 * wx0 * vy0 * vx0, w01 = wy0 * wx1 * vy0 * vx1;
            const float w10 = wy1 * wx0 * vy1 * vx0, w11 = wy1 * wx1 * vy1 * vx1;
            #pragma unroll
            for (int q = 0; q < 4; ++q) {
                unsigned pk[4];
                #pragma unroll
                for (int e = 0; e < 4; ++e) {
                    const int c0 = half * 32 + q * 8 + e * 2;
                    const float* __restrict__ xc0 = xb + (size_t)c0 * HW;
                    const float* __restrict__ xc1 = xc0 + HW;
                    const float s0 = w00 * xc0[l00] + w01 * xc0[l01] + w10 * xc0[l10] + w11 * xc0[l11];
                    const float s1 = w00 * xc1[l00] + w01 * xc1[l01] + w10 * xc1[l10] + w11 * xc1[l11];
                    pk[e] = f2bf(s0) | (f2bf(s1) << 16);
                }
                *(uint4*)(sT + swz(p, half * 64 + q * 16)) = make_uint4(pk[0], pk[1], pk[2], pk[3]);
            }
        }
        __syncthreads();
        #pragma unroll
        for (int ks = 0; ks < 2; ++ks)
            #pragma unroll
            for (int nt = 0; nt < 8; ++nt) {
                const int pc = nt * 16 + lrow;
                short8v bfr = *(const short8v*)(sT + swz(pc, ks * 64 + lk * 16));
                acc[nt] = __builtin_amdgcn_mfma_f32_16x16x32_bf16(afr[ks], bfr, acc[nt], 0, 0, 0);
            }
        __syncthreads();
    }

    float bv[4];
    #pragma unroll
    for (int j = 0; j < 4; ++j) bv[j] = bias[wv * 16 + lk * 4 + j];
    #pragma unroll
    for (int nt = 0; nt < 8; ++nt) {
        const int pc = nt * 16 + lrow;
        const float mmv = mmL[pc];
        #pragma unroll
        for (int j = 0; j < 4; ++j) {
            const int o = wv * 16 + lk * 4 + j;
            out[((size_t)(b * O + o)) * HW + ho * W + pc] = acc[nt][j] * mmv + bv[j];
        }
    }
}

} // namespace

extern "C" void kernel_launch(void* const* d_in, const int* in_sizes, int n_in,
                              void* d_out, int out_size, void* d_ws, size_t ws_size,
                              hipStream_t stream)
{
    const float* x  = (const float*)d_in[0];
    const float* w  = (const float*)d_in[1];
    const float* bs = (const float*)d_in[2];
    const float* ow = (const float*)d_in[3];
    const float* ob = (const float*)d_in[4];
    const float* mw = (const float*)d_in[5];
    const float* mb = (const float*)d_in[6];
    float* out = (float*)d_out;

    if (ws_size < WS_NEED) {
        dim3 grid(B * H), block(256);
        hipLaunchKernelGGL(dcn_fallback, grid, block, 0, stream,
                           x, w, bs, ow, ob, mw, mb, out);
        return;
    }

    unsigned char* ws = (unsigned char*)d_ws;
    hipLaunchKernelGGL(k0_pack, dim3(27), dim3(256), 0, stream, w, ow, mw, ws);
    hipLaunchKernelGGL(dcn_fused15, dim3(512), dim3(256), 0, stream,
                       x, bs, ob, mb, (const unsigned char*)ws, out);
}

// Round 18
// 41.091 us; speedup vs baseline: 1.1891x; 1.1891x over previous
//
#include <hip/hip_runtime.h>
#include <math.h>

namespace {

constexpr int B = 4, C = 64, O = 64, H = 128, W = 128, K2 = 9;
constexpr int HW = H * W;
constexpr int PIX = 128;   // fallback tile
constexpr int STR = 64;    // strip width (output px per block)
// window: rows ho-1..ho+2, cols wo0-2..wo0+64  (phase A needs x up to wo0+64)
constexpr int WROWS = 4, WCOLS = STR + 3, WCELLS = WROWS * WCOLS;  // 4x67 = 268 cells

typedef __attribute__((ext_vector_type(8))) short short8v;
typedef __attribute__((ext_vector_type(4))) float f32x4;
typedef __attribute__((ext_vector_type(2))) float f32x2;
typedef __attribute__((ext_vector_type(4))) unsigned u32x4;

__device__ __forceinline__ unsigned f2bf(float f) {
    unsigned u = __float_as_uint(f);
    return (u + 0x7FFFu + ((u >> 16) & 1u)) >> 16;
}
// packed f32x2 -> bf16x2 (RNE), single instruction
__device__ __forceinline__ unsigned cvtpk(float lo, float hi) {
    unsigned r;
    asm("v_cvt_pk_bf16_f32 %0, %1, %2" : "=v"(r) : "v"(lo), "v"(hi));
    return r;
}
// unpack bf16-pair dword -> f32x2 (lo = even channel)
__device__ __forceinline__ f32x2 up2(unsigned d) {
    f32x2 r;
    r[0] = __uint_as_float(d << 16);
    r[1] = __uint_as_float(d & 0xffff0000u);
    return r;
}
// swizzled byte offset: 128-B rows, XOR bank swizzle
__device__ __forceinline__ int swz(int r, int off) {
    return (r << 7) + (off ^ ((r & 7) << 4));
}

// workspace: packed weight fragments only
constexpr size_t WSW_OFF = 0;        // 4608 * 16 B  (main conv W-frags)
constexpr size_t WSA_OFF = 73728;    // 2304 * 16 B  (offset/mod conv A-frags)
constexpr size_t WS_NEED = 110592;

// ================= K0: pack weights into bf16 MFMA-fragment layout =================
__global__ void k0_pack(const float* __restrict__ w, const float* __restrict__ ow,
                        const float* __restrict__ mw, unsigned char* __restrict__ ws)
{
    const int id = blockIdx.x * 256 + threadIdx.x;
    if (id < 4608) {
        // wsW[k][ks][ot][lane]: o = ot*16+(lane&15), cb = ks*32+(lane>>4)*8
        const int k = id >> 9, rem = id & 511, ks = rem >> 8, r2 = rem & 255;
        const int ot = r2 >> 6, lane = r2 & 63;
        const int o = ot * 16 + (lane & 15), cb = ks * 32 + (lane >> 4) * 8;
        unsigned pk[4];
        #pragma unroll
        for (int e = 0; e < 4; ++e)
            pk[e] = f2bf(w[(o * C + cb + 2 * e) * 9 + k])
                  | (f2bf(w[(o * C + cb + 2 * e + 1) * 9 + k]) << 16);
        *(uint4*)(ws + WSW_OFF + (size_t)id * 16) = make_uint4(pk[0], pk[1], pk[2], pk[3]);
    } else if (id < 6912) {
        // wsA[k][ks][mt][lane]: r = mt*16+(lane&15) (27 rows used, pad 32)
        const int id2 = id - 4608;
        const int k = id2 >> 8, rem = id2 & 255, ks = rem >> 7, r2 = rem & 127;
        const int mt = r2 >> 6, lane = r2 & 63;
        const int r = mt * 16 + (lane & 15), cb = ks * 32 + (lane >> 4) * 8;
        unsigned pk[4];
        #pragma unroll
        for (int e = 0; e < 4; ++e) {
            float v0 = 0.f, v1 = 0.f;
            const int c0 = cb + 2 * e;
            if (r < 18)      { v0 = ow[(r * C + c0) * 9 + k];        v1 = ow[(r * C + c0 + 1) * 9 + k]; }
            else if (r < 27) { v0 = mw[((r - 18) * C + c0) * 9 + k]; v1 = mw[((r - 18) * C + c0 + 1) * 9 + k]; }
            pk[e] = f2bf(v0) | (f2bf(v1) << 16);
        }
        *(uint4*)(ws + WSA_OFF + (size_t)id2 * 16) = make_uint4(pk[0], pk[1], pk[2], pk[3]);
    }
}

// ====== fused: 64-px strip; 4x67 window; af double-buffer software pipeline ======
__global__ __launch_bounds__(256, 3)
void dcn_fused14(const float* __restrict__ x, const float* __restrict__ bias,
                 const float* __restrict__ ob, const float* __restrict__ mb,
                 const unsigned char* __restrict__ ws, float* __restrict__ out)
{
    __shared__ __align__(16) unsigned char sW[WCELLS * 128]; // bf16 [cell][ch] window, 34304 B
    __shared__ float offL[18 * STR];                          // sy/sx only, 4608 B

    const int tid = threadIdx.x;
    const int lane = tid & 63, wv = tid >> 6;
    const int lrow = lane & 15, lk = lane >> 4;

    // XCD-aware bijective swizzle (1024 % 8 == 0)
    const int raw = blockIdx.x;
    const int bid = (raw & 7) * 128 + (raw >> 3);
    const int b = bid >> 8;
    const int s = bid & 255;
    const int ho = s >> 1;
    const int wo0 = (s & 1) * STR;

    const float* __restrict__ xb = x + b * C * HW;

    // ---- stage window: rows ho-1..ho+2, cols wo0-2..wo0+64, 64 ch, bf16, ONCE ----
    for (int t = tid; t < 2 * WCELLS; t += 256) {      // 536 units (cell, 32-ch half)
        const int cell = t >> 1, chalf = t & 1;
        const int row = cell / WCOLS, col = cell - row * WCOLS;
        const int y = ho - 1 + row, xg = wo0 - 2 + col;
        const bool v = (y >= 0) & (y < H) & (xg >= 0) & (xg < W);
        const float vf = v ? 1.f : 0.f;
        const float* __restrict__ xp = xb + (v ? (y * W + xg) : 0);
        #pragma unroll
        for (int q = 0; q < 4; ++q) {
            unsigned pk[4];
            #pragma unroll
            for (int e = 0; e < 4; ++e) {
                const int c0 = chalf * 32 + q * 8 + 2 * e;
                pk[e] = cvtpk(vf * xp[c0 * HW], vf * xp[(c0 + 1) * HW]);
            }
            *(uint4*)(sW + swz(cell, chalf * 64 + q * 16)) = make_uint4(pk[0], pk[1], pk[2], pk[3]);
        }
    }
    __syncthreads();   // #1: window ready

    // ---- phase A MFMA: wave w owns px-cols w*16..w*16+15, M = 32 (27 used) ----
    f32x4 oacc[2];
    #pragma unroll
    for (int mt = 0; mt < 2; ++mt)
        #pragma unroll
        for (int j = 0; j < 4; ++j) oacc[mt][j] = 0.f;

    #pragma unroll
    for (int k = 0; k < 9; ++k) {
        const int ky = k / 3, kx = k - ky * 3;
        const int cellb = ky * WCOLS + (wv * 16 + lrow) + kx + 1;   // col <= 66 OK
        #pragma unroll
        for (int ks = 0; ks < 2; ++ks) {
            short8v bf = *(const short8v*)(sW + swz(cellb, ks * 64 + lk * 16));
            #pragma unroll
            for (int mt = 0; mt < 2; ++mt) {
                short8v af = *(const short8v*)(ws + WSA_OFF +
                    (size_t)((((k * 2 + ks) * 2 + mt) * 64 + lane)) * 16);
                oacc[mt] = __builtin_amdgcn_mfma_f32_16x16x32_bf16(af, bf, oacc[mt], 0, 0, 0);
            }
        }
    }

    // ---- positions into LDS (18 rows) + in-register modulation mean ----
    float mpart = 0.f;
    {
        const int pc = wv * 16 + lrow;
        #pragma unroll
        for (int mt = 0; mt < 2; ++mt) {
            #pragma unroll
            for (int j = 0; j < 4; ++j) {
                const int r = mt * 16 + lk * 4 + j;
                const float val = oacc[mt][j];
                if (r < 9)       offL[r * STR + pc] = (float)ho + ob[r] + val;         // sy
                else if (r < 18) offL[r * STR + pc] = (float)(wo0 + pc) + ob[r] + val; // sx
                else if (r < 27) mpart += 1.f / (1.f + __expf(-(val + mb[r - 18])));   // mod
            }
        }
    }
    // reduce mod partials across the 4 lk-groups (same lrow -> same px)
    mpart += __shfl_xor(mpart, 16);
    mpart += __shfl_xor(mpart, 32);
    const float mm = mpart * (1.f / 9.f);
    __syncthreads();   // #2: offL ready (window untouched) — last barrier

    // ---- phase B: per-wave, barrier-free. Wave owns px = wv*16 + lrow. ----
    const int px = wv * 16 + lrow;

    // preload ALL sy/sx into registers (18 independent ds_reads)
    float syr[9], sxr[9];
    #pragma unroll
    for (int k = 0; k < 9; ++k) {
        syr[k] = offL[k * STR + px];
        sxr[k] = offL[(9 + k) * STR + px];
    }

    f32x4 acc[4];      // o-tiles 0..3 (all 64 outputs for this wave's 16 px)
    #pragma unroll
    for (int ot = 0; ot < 4; ++ot)
        #pragma unroll
        for (int j = 0; j < 4; ++j) acc[ot][j] = 0.f;

    // af software pipeline: double-buffered 8-fragment sets (tap k+1 issued before tap k's MFMAs)
    short8v afq[8], afn[8];
    #pragma unroll
    for (int i = 0; i < 8; ++i)
        afq[i] = *(const short8v*)(ws + WSW_OFF + (size_t)(i * 64 + lane) * 16);

    #pragma unroll
    for (int k = 0; k < 9; ++k) {
        const float syv = syr[k];
        const float sxv = sxr[k];
        const float fy = floorf(syv), fx = floorf(sxv);
        const float wy1 = syv - fy, wx1 = sxv - fx;
        const float wy0 = 1.f - wy1, wx0 = 1.f - wx1;
        const int y0 = (int)fy, x0 = (int)fx;
        const int rw = y0 - (ho - 1), cw = x0 - (wo0 - 2);
        const bool inw = (rw >= 0) & (rw <= WROWS - 2) & (cw >= 0) & (cw <= WCOLS - 2);
        const float u00 = wy0 * wx0, u01 = wy0 * wx1;
        const float u10 = wy1 * wx0, u11 = wy1 * wx1;

        short8v bfrag[2];
        if (__builtin_expect(inw, 1)) {
            const int c00 = rw * WCOLS + cw;
            #pragma unroll
            for (int ks = 0; ks < 2; ++ks) {
                const int chOff = ks * 64 + lk * 16;
                const uint4 d00 = *(const uint4*)(sW + swz(c00,             chOff));
                const uint4 d01 = *(const uint4*)(sW + swz(c00 + 1,         chOff));
                const uint4 d10 = *(const uint4*)(sW + swz(c00 + WCOLS,     chOff));
                const uint4 d11 = *(const uint4*)(sW + swz(c00 + WCOLS + 1, chOff));
                // packed bilinear per channel-pair, cvt_pk to bf16x2
                auto bil = [&](unsigned a, unsigned bb, unsigned c, unsigned d) -> unsigned {
                    f32x2 sacc = up2(a);
                    sacc *= u00;
                    sacc += up2(bb) * u01;
                    sacc += up2(c)  * u10;
                    sacc += up2(d)  * u11;
                    return cvtpk(sacc[0], sacc[1]);
                };
                u32x4 wvv;
                wvv[0] = bil(d00.x, d01.x, d10.x, d11.x);
                wvv[1] = bil(d00.y, d01.y, d10.y, d11.y);
                wvv[2] = bil(d00.z, d01.z, d10.z, d11.z);
                wvv[3] = bil(d00.w, d01.w, d10.w, d11.w);
                bfrag[ks] = __builtin_bit_cast(short8v, wvv);
            }
        } else {
            // exact global fallback (validity-weighted, clamped) — cold path
            const float vy0 = (y0 >= 0 && y0 < H) ? 1.f : 0.f;
            const float vy1 = (y0 + 1 >= 0 && y0 + 1 < H) ? 1.f : 0.f;
            const float vx0 = (x0 >= 0 && x0 < W) ? 1.f : 0.f;
            const float vx1 = (x0 + 1 >= 0 && x0 + 1 < W) ? 1.f : 0.f;
            const int cy0 = min(max(y0, 0), H - 1), cy1 = min(max(y0 + 1, 0), H - 1);
            const int cx0 = min(max(x0, 0), W - 1), cx1 = min(max(x0 + 1, 0), W - 1);
            const int l00 = cy0 * W + cx0, l01 = cy0 * W + cx1;
            const int l10 = cy1 * W + cx0, l11 = cy1 * W + cx1;
            const float g00 = u00 * vy0 * vx0, g01 = u01 * vy0 * vx1;
            const float g10 = u10 * vy1 * vx0, g11 = u11 * vy1 * vx1;
            #pragma unroll
            for (int ks = 0; ks < 2; ++ks) {
                #pragma unroll
                for (int j = 0; j < 8; ++j) {
                    const float* __restrict__ xc = xb + (ks * 32 + lk * 8 + j) * HW;
                    const float sv = g00 * xc[l00] + g01 * xc[l01]
                                   + g10 * xc[l10] + g11 * xc[l11];
                    bfrag[ks][j] = (short)f2bf(sv);
                }
            }
        }

        // prefetch next tap's af fragments BEFORE this tap's MFMAs
        if (k < 8) {
            #pragma unroll
            for (int i = 0; i < 8; ++i)
                afn[i] = *(const short8v*)(ws + WSW_OFF +
                    (size_t)(((k + 1) * 8 + i) * 64 + lane) * 16);
        }

        // 8 MFMAs: i = ks*4+ot (same accumulation order as before)
        #pragma unroll
        for (int i = 0; i < 8; ++i)
            acc[i & 3] = __builtin_amdgcn_mfma_f32_16x16x32_bf16(
                afq[i], bfrag[i >> 2], acc[i & 3], 0, 0, 0);

        if (k < 8) {
            #pragma unroll
            for (int i = 0; i < 8; ++i) afq[i] = afn[i];
        }
    }

    // ---- epilogue: modulate (mm in register), bias, store ----
    #pragma unroll
    for (int ot = 0; ot < 4; ++ot) {
        #pragma unroll
        for (int j = 0; j < 4; ++j) {
            const int o = ot * 16 + lk * 4 + j;
            out[(b * O + o) * HW + ho * W + wo0 + px] = acc[ot][j] * mm + bias[o];
        }
    }
}

// ================= fallback (round-2 kernel, used if ws too small) =================
__global__ __launch_bounds__(256, 2)
void dcn_fallback(const float* __restrict__ x, const float* __restrict__ weight,
                  const float* __restrict__ bias, const float* __restrict__ ow,
                  const float* __restrict__ ob, const float* __restrict__ mw,
                  const float* __restrict__ mb, float* __restrict__ out)
{
    __shared__ __align__(16) unsigned char sT[PIX * 128];
    __shared__ float offL[32 * PIX];
    __shared__ float mmL[PIX];

    const int tid = threadIdx.x;
    const int lane = tid & 63;
    const int wv = tid >> 6;
    const int bid = (blockIdx.x & 7) * 64 + (blockIdx.x >> 3);
    const int b = bid >> 7;
    const int ho = bid & 127;
    const float* __restrict__ xb = x + (size_t)b * C * HW;
    const int p = tid & 127, half = tid >> 7, wo = p;
    const int lrow = lane & 15, lk = lane >> 4;

    f32x4 oacc[2][2];
    #pragma unroll
    for (int mt = 0; mt < 2; ++mt)
        #pragma unroll
        for (int nt = 0; nt < 2; ++nt)
            #pragma unroll
            for (int j = 0; j < 4; ++j) oacc[mt][nt][j] = 0.0f;

    #pragma unroll
    for (int k = 0; k < K2; ++k) {
        const int ky = k / 3, kx = k % 3;
        short8v afrA[2][2];
        #pragma unroll
        for (int ks = 0; ks < 2; ++ks)
            #pragma unroll
            for (int mt = 0; mt < 2; ++mt) {
                const int r = mt * 16 + lrow, cb = ks * 32 + lk * 8;
                #pragma unroll
                for (int j = 0; j < 8; ++j) {
                    float wvv = 0.0f;
                    if (r < 18)      wvv = ow[((size_t)(r * C + cb + j)) * 9 + k];
                    else if (r < 27) wvv = mw[((size_t)((r - 18) * C + cb + j)) * 9 + k];
                    afrA[ks][mt][j] = (short)f2bf(wvv);
                }
            }
        {
            const int y = ho - 1 + ky, xx = wo - 1 + kx;
            const bool v = (y >= 0) & (y < H) & (xx >= 0) & (xx < W);
            const float vf = v ? 1.0f : 0.0f;
            const float* __restrict__ xp = xb + (v ? (y * W + xx) : 0);
            #pragma unroll
            for (int q = 0; q < 4; ++q) {
                unsigned pk[4];
                #pragma unroll
                for (int e = 0; e < 4; ++e) {
                    const int c0 = half * 32 + q * 8 + e * 2;
                    pk[e] = f2bf(vf * xp[(size_t)c0 * HW]) | (f2bf(vf * xp[(size_t)(c0 + 1) * HW]) << 16);
                }
                *(uint4*)(sT + swz(p, half * 64 + q * 16)) = make_uint4(pk[0], pk[1], pk[2], pk[3]);
            }
        }
        __syncthreads();
        #pragma unroll
        for (int ks = 0; ks < 2; ++ks)
            #pragma unroll
            for (int nt = 0; nt < 2; ++nt) {
                const int pc = wv * 32 + nt * 16 + lrow;
                short8v bfr = *(const short8v*)(sT + swz(pc, ks * 64 + lk * 16));
                #pragma unroll
                for (int mt = 0; mt < 2; ++mt)
                    oacc[mt][nt] = __builtin_amdgcn_mfma_f32_16x16x32_bf16(afrA[ks][mt], bfr, oacc[mt][nt], 0, 0, 0);
            }
        __syncthreads();
    }

    #pragma unroll
    for (int mt = 0; mt < 2; ++mt)
        #pragma unroll
        for (int nt = 0; nt < 2; ++nt)
            #pragma unroll
            for (int j = 0; j < 4; ++j) {
                const int r = mt * 16 + lk * 4 + j;
                const int pc = wv * 32 + nt * 16 + lrow;
                float bv = 0.0f;
                if (r < 18)      bv = ob[r];
                else if (r < 27) bv = mb[r - 18];
                offL[r * PIX + pc] = oacc[mt][nt][j] + bv;
            }
    __syncthreads();

    float sy[K2], sx[K2];
    #pragma unroll
    for (int k = 0; k < K2; ++k) {
        sy[k] = (float)ho + offL[k * PIX + p];
        sx[k] = (float)wo + offL[(9 + k) * PIX + p];
    }
    if (half == 0) {
        float mm = 0.0f;
        #pragma unroll
        for (int k = 0; k < K2; ++k)
            mm += 1.0f / (1.0f + __expf(-offL[(18 + k) * PIX + p]));
        mmL[p] = mm * (1.0f / 9.0f);
    }

    f32x4 acc[8];
    #pragma unroll
    for (int nt = 0; nt < 8; ++nt)
        #pragma unroll
        for (int j = 0; j < 4; ++j) acc[nt][j] = 0.0f;

    #pragma unroll
    for (int k = 0; k < K2; ++k) {
        short8v afr[2];
        #pragma unroll
        for (int ks = 0; ks < 2; ++ks) {
            const int o = wv * 16 + lrow, cb = ks * 32 + lk * 8;
            #pragma unroll
            for (int j = 0; j < 8; ++j)
                afr[ks][j] = (short)f2bf(weight[((size_t)(o * C + cb + j)) * 9 + k]);
        }
        {
            const float fy = floorf(sy[k]), fx = floorf(sx[k]);
            const float wy1 = sy[k] - fy, wx1 = sx[k] - fx;
            const float wy0 = 1.0f - wy1, wx0 = 1.0f - wx1;
            const int y0 = (int)fy, x0 = (int)fx, y1 = y0 + 1, x1 = x0 + 1;
            const float vy0 = (y0 >= 0 && y0 < H) ? 1.0f : 0.0f;
            const float vy1 = (y1 >= 0 && y1 < H) ? 1.0f : 0.0f;
            const float vx0 = (x0 >= 0 && x0 < W) ? 1.0f : 0.0f;
            const float vx1 = (x1 >= 0 && x1 < W) ? 1.0f : 0.0f;
            const int cy0 = min(max(y0, 0), H - 1), cy1 = min(max(y1, 0), H - 1);
            const int cx0 = min(max(x0, 0), W - 1), cx1 = min(max(x1, 0), W - 1);
            const int l00 = cy0 * W + cx0, l01 = cy0 * W + cx1;
            const int l10 = cy1 * W + cx0, l11 = cy1 * W + cx1;
            const float w00 = wy0 * wx0 * vy0 * vx0, w01 = wy0 * wx1 * vy0 * vx1;
            const float w10 = wy1 * wx0 * vy1 * vx0, w11 = wy1 * wx1 * vy1 * vx1;
            #pragma unroll
            for (int q = 0; q < 4; ++q) {
                unsigned pk[4];
                #pragma unroll
                for (int e = 0; e < 4; ++e) {
                    const int c0 = half * 32 + q * 8 + e * 2;
                    const float* __restrict__ xc0 = xb + (size_t)c0 * HW;
                    const float* __restrict__ xc1 = xc0 + HW;
                    const float s0 = w00 * xc0[l00] + w01 * xc0[l01] + w10 * xc0[l10] + w11 * xc0[l11];
                    const float s1 = w00 * xc1[l00] + w01 * xc1[l01] + w10 * xc1[l10] + w11 * xc1[l11];
                    pk[e] = f2bf(s0) | (f2bf(s1) << 16);
                }
                *(uint4*)(sT + swz(p, half * 64 + q * 16)) = make_uint4(pk[0], pk[1], pk[2], pk[3]);
            }
        }
        __syncthreads();
        #pragma unroll
        for (int ks = 0; ks < 2; ++ks)
            #pragma unroll
            for (int nt = 0; nt < 8; ++nt) {
                const int pc = nt * 16 + lrow;
                short8v bfr = *(const short8v*)(sT + swz(pc, ks * 64 + lk * 16));
                acc[nt] = __builtin_amdgcn_mfma_f32_16x16x32_bf16(afr[ks], bfr, acc[nt], 0, 0, 0);
            }
        __syncthreads();
    }

    float bv[4];
    #pragma unroll
    for (int j = 0; j < 4; ++j) bv[j] = bias[wv * 16 + lk * 4 + j];
    #pragma unroll
    for (int nt = 0; nt < 8; ++nt) {
        const int pc = nt * 16 + lrow;
        const float mmv = mmL[pc];
        #pragma unroll
        for (int j = 0; j < 4; ++j) {
            const int o = wv * 16 + lk * 4 + j;
            out[((size_t)(b * O + o)) * HW + ho * W + pc] = acc[nt][j] * mmv + bv[j];
        }
    }
}

} // namespace

extern "C" void kernel_launch(void* const* d_in, const int* in_sizes, int n_in,
                              void* d_out, int out_size, void* d_ws, size_t ws_size,
                              hipStream_t stream)
{
    const float* x  = (const float*)d_in[0];
    const float* w  = (const float*)d_in[1];
    const float* bs = (const float*)d_in[2];
    const float* ow = (const float*)d_in[3];
    const float* ob = (const float*)d_in[4];
    const float* mw = (const float*)d_in[5];
    const float* mb = (const float*)d_in[6];
    float* out = (float*)d_out;

    if (ws_size < WS_NEED) {
        dim3 grid(B * H), block(256);
        hipLaunchKernelGGL(dcn_fallback, grid, block, 0, stream,
                           x, w, bs, ow, ob, mw, mb, out);
        return;
    }

    unsigned char* ws = (unsigned char*)d_ws;
    hipLaunchKernelGGL(k0_pack, dim3(27), dim3(256), 0, stream, w, ow, mw, ws);
    hipLaunchKernelGGL(dcn_fused14, dim3(1024), dim3(256), 0, stream,
                       x, bs, ob, mb, (const unsigned char*)ws, out);
}